// Round 1
// baseline (390.233 us; speedup 1.0000x reference)
//
#include <hip/hip_runtime.h>
#include <cstdint>
#include <cstddef>

typedef unsigned short u16;
typedef __attribute__((ext_vector_type(8))) short bf16x8;
typedef __attribute__((ext_vector_type(4))) float f32x4;

__device__ inline float bf2f(u16 u) { return __uint_as_float(((unsigned)u) << 16); }
__device__ inline u16 f2bf(float f) {
  unsigned u = __float_as_uint(f);
  u += 0x7fffu + ((u >> 16) & 1u);   // RNE
  return (u16)(u >> 16);
}

__device__ inline void async16(const u16* g, u16* l) {
  __builtin_amdgcn_global_load_lds(
      (const __attribute__((address_space(1))) void*)g,
      (__attribute__((address_space(3))) void*)l, 16, 0, 0);
}

__device__ inline void load4bf(const u16* p, size_t idx, float* o) {
  uint2 q = *(const uint2*)(p + idx);
  o[0] = bf2f((u16)(q.x & 0xffffu));
  o[1] = bf2f((u16)(q.x >> 16));
  o[2] = bf2f((u16)(q.y & 0xffffu));
  o[3] = bf2f((u16)(q.y >> 16));
}

template <int NQ>
__device__ inline void block_reduce_bcast(float* v, float* bc, int t) {
  __shared__ float red[NQ][4];
  const int lane = t & 63, w = t >> 6;
#pragma unroll
  for (int q = 0; q < NQ; q++) {
#pragma unroll
    for (int off = 32; off; off >>= 1) v[q] += __shfl_down(v[q], off, 64);
  }
  if (lane == 0) {
#pragma unroll
    for (int q = 0; q < NQ; q++) red[q][w] = v[q];
  }
  __syncthreads();
  if (t < NQ) bc[t] = red[t][0] + red[t][1] + red[t][2] + red[t][3];
  __syncthreads();
}

// ---------------- fp32 -> bf16 convert ----------------
struct ConvArgs { const float* src[6]; u16* dst[6]; };

__global__ __launch_bounds__(256) void convert_bf16(ConvArgs a, int n) {
  const int which = blockIdx.y;
  const float* __restrict__ s = a.src[which];
  u16* __restrict__ d = a.dst[which];
  const int i = (blockIdx.x * 256 + threadIdx.x) * 4;
  if (i >= n) return;
  float4 v = *(const float4*)(s + i);
  uint2 o;
  o.x = (unsigned)f2bf(v.x) | ((unsigned)f2bf(v.y) << 16);
  o.y = (unsigned)f2bf(v.z) | ((unsigned)f2bf(v.w) << 16);
  *(uint2*)(d + i) = o;
}

// ---------------- bf16 NT GEMM: Y = A @ W^T, A[M][K], W[N][K], all K-major ----------------
struct GemmArgs { const u16* A[5]; const u16* Bw[5]; u16* Y[5]; };

__global__ __launch_bounds__(256) void gemm_bt(GemmArgs args, int K) {
  const int gate = blockIdx.z;
  const u16* __restrict__ A  = args.A[gate];
  const u16* __restrict__ Bw = args.Bw[gate];
  u16* __restrict__ Y = args.Y[gate];

  __shared__ __attribute__((aligned(16))) u16 As[128 * 32];
  __shared__ __attribute__((aligned(16))) u16 Bs[128 * 32];

  const int tid  = threadIdx.x;
  const int lane = tid & 63;
  const int w    = tid >> 6;   // wave 0..3
  const int wm   = w >> 1;     // wave quadrant row
  const int wn   = w & 1;      // wave quadrant col

  const int rowBlk = blockIdx.y * 128;
  const int colBlk = blockIdx.x * 128;

  // staging: lane l covers (row = r0 + l/4, k-chunk = (l%4)*8) -> LDS row-major [128][32], no pad
  const int lrow = lane >> 2;
  const int lcol = (lane & 3) * 8;
  const int r0a = w * 16;
  const int r0b = 64 + w * 16;

  const u16* gA0 = A  + (size_t)(rowBlk + r0a + lrow) * K + lcol;
  const u16* gA1 = A  + (size_t)(rowBlk + r0b + lrow) * K + lcol;
  const u16* gB0 = Bw + (size_t)(colBlk + r0a + lrow) * K + lcol;
  const u16* gB1 = Bw + (size_t)(colBlk + r0b + lrow) * K + lcol;
  u16* lA0 = &As[r0a * 32];
  u16* lA1 = &As[r0b * 32];
  u16* lB0 = &Bs[r0a * 32];
  u16* lB1 = &Bs[r0b * 32];

  // fragment read offsets: A operand m=lane&15, k=(lane>>4)*8+j (K-contiguous b128)
  const int aoff = (wm * 64 + (lane & 15)) * 32 + (lane >> 4) * 8;
  const int boff = (wn * 64 + (lane & 15)) * 32 + (lane >> 4) * 8;

  f32x4 acc[4][4] = {};

  for (int k0 = 0; k0 < K; k0 += 32) {
    async16(gA0 + k0, lA0);
    async16(gA1 + k0, lA1);
    async16(gB0 + k0, lB0);
    async16(gB1 + k0, lB1);
    __syncthreads();
    bf16x8 af[4], bfr[4];
#pragma unroll
    for (int t = 0; t < 4; t++) {
      af[t]  = *(const bf16x8*)&As[aoff + t * 16 * 32];
      bfr[t] = *(const bf16x8*)&Bs[boff + t * 16 * 32];
    }
#pragma unroll
    for (int tm = 0; tm < 4; tm++)
#pragma unroll
      for (int tn = 0; tn < 4; tn++)
        acc[tm][tn] = __builtin_amdgcn_mfma_f32_16x16x32_bf16(af[tm], bfr[tn], acc[tm][tn], 0, 0, 0);
    __syncthreads();
  }

  // C/D: row = (lane>>4)*4 + reg, col = lane&15  (verified m89/m91)
  const int rBase = rowBlk + wm * 64 + (lane >> 4) * 4;
  const int cBase = colBlk + wn * 64 + (lane & 15);
#pragma unroll
  for (int tm = 0; tm < 4; tm++) {
#pragma unroll
    for (int i = 0; i < 4; i++) {
      const size_t r = (size_t)(rBase + tm * 16 + i);
#pragma unroll
      for (int tn = 0; tn < 4; tn++)
        Y[r * 1024 + cBase + tn * 16] = f2bf(acc[tm][tn][i]);
    }
  }
}

// ---------------- stage 2: r = sigmoid(ln(Yrh)+ln(Yrx)); hr = h*r ----------------
__global__ __launch_bounds__(256) void rgate_kernel(
    const u16* __restrict__ Yrh, const u16* __restrict__ Yrx,
    const float* __restrict__ h, const float* __restrict__ gamma,
    const float* __restrict__ beta, u16* __restrict__ hrb) {
  const int row = blockIdx.x;
  const int t = threadIdx.x;
  const int c0 = t * 4;
  const size_t base = (size_t)row * 1024 + c0;

  float a[4], b[4];
  load4bf(Yrh, base, a);
  load4bf(Yrx, base, b);

  float v[4] = {0.f, 0.f, 0.f, 0.f};
#pragma unroll
  for (int j = 0; j < 4; j++) {
    v[0] += a[j]; v[1] += a[j] * a[j];
    v[2] += b[j]; v[3] += b[j] * b[j];
  }
  __shared__ float bc[4];
  block_reduce_bcast<4>(v, bc, t);

  const float inv = 1.0f / 1024.0f;
  const float mu0 = bc[0] * inv, rs0 = rsqrtf(bc[1] * inv - mu0 * mu0 + 1e-5f);
  const float mu1 = bc[2] * inv, rs1 = rsqrtf(bc[3] * inv - mu1 * mu1 + 1e-5f);

  unsigned pack[2];
#pragma unroll
  for (int j = 0; j < 4; j++) {
    const int c = c0 + j;
    const float ln0 = (a[j] - mu0) * rs0 * gamma[c] + beta[c];
    const float ln1 = (b[j] - mu1) * rs1 * gamma[1024 + c] + beta[1024 + c];
    const float r = 1.0f / (1.0f + expf(-(ln0 + ln1)));
    const float hr = h[base + j] * r;
    const unsigned bb = (unsigned)f2bf(hr);
    if (j & 1) pack[j >> 1] |= bb << 16; else pack[j >> 1] = bb;
  }
  uint2 o; o.x = pack[0]; o.y = pack[1];
  *(uint2*)(hrb + base) = o;   // aliases Yrx: each column read & written by the same thread only
}

// ---------------- stage 4: u, c, out ----------------
__global__ __launch_bounds__(256) void final_fuse(
    const u16* __restrict__ Yuh, const u16* __restrict__ Yux,
    const u16* __restrict__ Ych, const u16* __restrict__ Ycx,
    const float* __restrict__ h, const float* __restrict__ gamma,
    const float* __restrict__ beta, float* __restrict__ out) {
  const int row = blockIdx.x;
  const int t = threadIdx.x;
  const int c0 = t * 4;
  const size_t base = (size_t)row * 1024 + c0;

  float a0[4], a1[4], a2[4], a3[4];
  load4bf(Yuh, base, a0);
  load4bf(Yux, base, a1);
  load4bf(Ych, base, a2);
  load4bf(Ycx, base, a3);

  float v[8] = {0.f, 0.f, 0.f, 0.f, 0.f, 0.f, 0.f, 0.f};
#pragma unroll
  for (int j = 0; j < 4; j++) {
    v[0] += a0[j]; v[1] += a0[j] * a0[j];
    v[2] += a1[j]; v[3] += a1[j] * a1[j];
    v[4] += a2[j]; v[5] += a2[j] * a2[j];
    v[6] += a3[j]; v[7] += a3[j] * a3[j];
  }
  __shared__ float bc[8];
  block_reduce_bcast<8>(v, bc, t);

  const float inv = 1.0f / 1024.0f;
  const float mu0 = bc[0] * inv, rs0 = rsqrtf(bc[1] * inv - mu0 * mu0 + 1e-5f);
  const float mu1 = bc[2] * inv, rs1 = rsqrtf(bc[3] * inv - mu1 * mu1 + 1e-5f);
  const float mu2 = bc[4] * inv, rs2 = rsqrtf(bc[5] * inv - mu2 * mu2 + 1e-5f);
  const float mu3 = bc[6] * inv, rs3 = rsqrtf(bc[7] * inv - mu3 * mu3 + 1e-5f);

  float o[4];
#pragma unroll
  for (int j = 0; j < 4; j++) {
    const int c = c0 + j;
    const float ln2 = (a0[j] - mu0) * rs0 * gamma[2 * 1024 + c] + beta[2 * 1024 + c];
    const float ln3 = (a1[j] - mu1) * rs1 * gamma[3 * 1024 + c] + beta[3 * 1024 + c];
    const float ln4 = (a2[j] - mu2) * rs2 * gamma[4 * 1024 + c] + beta[4 * 1024 + c];
    const float ln5 = (a3[j] - mu3) * rs3 * gamma[5 * 1024 + c] + beta[5 * 1024 + c];
    const float u = 1.0f / (1.0f + expf(-(ln2 + ln3)));
    const float cg = tanhf(ln4 + ln5);
    const float hj = h[base + j];
    o[j] = (1.0f - u) * hj + u * cg;
  }
  float4 ov; ov.x = o[0]; ov.y = o[1]; ov.z = o[2]; ov.w = o[3];
  *(float4*)(out + base) = ov;
}

extern "C" void kernel_launch(void* const* d_in, const int* in_sizes, int n_in,
                              void* d_out, int out_size, void* d_ws, size_t ws_size,
                              hipStream_t stream) {
  const float* x  = (const float*)d_in[0];
  const float* h  = (const float*)d_in[1];
  const float* Ws[6] = {(const float*)d_in[2], (const float*)d_in[3],
                        (const float*)d_in[4], (const float*)d_in[5],
                        (const float*)d_in[6], (const float*)d_in[7]};
  const float* gamma = (const float*)d_in[8];
  const float* beta  = (const float*)d_in[9];
  float* out = (float*)d_out;

  char* ws = (char*)d_ws;
  const size_t SZ_ACT = (size_t)8192 * 1024 * 2;  // 16 MiB (bf16 activation/Y)
  const size_t SZ_W   = (size_t)1024 * 1024 * 2;  // 2 MiB  (bf16 weight)

  u16* xb = (u16*)(ws);
  u16* hb = (u16*)(ws + SZ_ACT);
  u16* wb[6];
  for (int i = 0; i < 6; i++) wb[i] = (u16*)(ws + 2 * SZ_ACT + i * SZ_W);
  char* ybase = ws + 2 * SZ_ACT + 6 * SZ_W;
  u16* Y0 = (u16*)(ybase);                 // r_hidden; reused for c_hidden
  u16* Y1 = (u16*)(ybase + SZ_ACT);        // r_input;  reused for hr
  u16* Y2 = (u16*)(ybase + 2 * SZ_ACT);    // u_hidden
  u16* Y3 = (u16*)(ybase + 3 * SZ_ACT);    // u_input
  u16* Y5 = (u16*)(ybase + 4 * SZ_ACT);    // c_input
  // total ws use: 2*16 + 12 + 5*16 = 124 MiB

  // 1) converts
  ConvArgs ca = {};
  ca.src[0] = x; ca.dst[0] = xb;
  ca.src[1] = h; ca.dst[1] = hb;
  convert_bf16<<<dim3(8192, 2), 256, 0, stream>>>(ca, 8192 * 1024);
  ConvArgs cw = {};
  for (int i = 0; i < 6; i++) { cw.src[i] = Ws[i]; cw.dst[i] = wb[i]; }
  convert_bf16<<<dim3(1024, 6), 256, 0, stream>>>(cw, 1024 * 1024);

  // 2) batched stage-1 GEMMs: r_h, r_x, u_h, u_x, c_x
  GemmArgs g = {};
  g.A[0] = hb; g.Bw[0] = wb[0]; g.Y[0] = Y0;   // h @ W_r^T
  g.A[1] = xb; g.Bw[1] = wb[1]; g.Y[1] = Y1;   // x @ U_r^T
  g.A[2] = hb; g.Bw[2] = wb[2]; g.Y[2] = Y2;   // h @ W_u^T
  g.A[3] = xb; g.Bw[3] = wb[3]; g.Y[3] = Y3;   // x @ U_u^T
  g.A[4] = xb; g.Bw[4] = wb[5]; g.Y[4] = Y5;   // x @ U_c^T
  gemm_bt<<<dim3(8, 64, 5), 256, 0, stream>>>(g, 1024);

  // 3) r gate + hr (hr overwrites Y1, safe: per-thread read-before-write)
  rgate_kernel<<<8192, 256, 0, stream>>>(Y0, Y1, h, gamma, beta, Y1);

  // 4) c_hidden GEMM: hr @ W_c^T -> Y0 (Y0 dead after rgate)
  GemmArgs g2 = {};
  g2.A[0] = Y1; g2.Bw[0] = wb[4]; g2.Y[0] = Y0;
  gemm_bt<<<dim3(8, 64, 1), 256, 0, stream>>>(g2, 1024);

  // 5) u, c, out
  final_fuse<<<8192, 256, 0, stream>>>(Y2, Y3, Y0, Y5, h, gamma, beta, out);
}

// Round 2
// 315.965 us; speedup vs baseline: 1.2350x; 1.2350x over previous
//
#include <hip/hip_runtime.h>
#include <cstdint>
#include <cstddef>

typedef unsigned short u16;
typedef __attribute__((ext_vector_type(8))) short bf16x8;
typedef __attribute__((ext_vector_type(4))) float f32x4;

__device__ inline float bf2f(u16 u) { return __uint_as_float(((unsigned)u) << 16); }
__device__ inline u16 f2bf(float f) {
  unsigned u = __float_as_uint(f);
  u += 0x7fffu + ((u >> 16) & 1u);   // RNE
  return (u16)(u >> 16);
}

__device__ inline void async16(const u16* g, u16* l) {
  __builtin_amdgcn_global_load_lds(
      (const __attribute__((address_space(1))) void*)g,
      (__attribute__((address_space(3))) void*)l, 16, 0, 0);
}

__device__ inline void load4bf(const u16* p, size_t idx, float* o) {
  uint2 q = *(const uint2*)(p + idx);
  o[0] = bf2f((u16)(q.x & 0xffffu));
  o[1] = bf2f((u16)(q.x >> 16));
  o[2] = bf2f((u16)(q.y & 0xffffu));
  o[3] = bf2f((u16)(q.y >> 16));
}

__device__ inline float fast_sigmoid(float z) {
  return 1.0f / (1.0f + exp2f(-1.4426950408889634f * z));
}
__device__ inline float fast_tanh(float z) {
  return 1.0f - 2.0f / (1.0f + exp2f(2.8853900817779268f * z));
}

template <int NQ>
__device__ inline void block_reduce_bcast(float* v, float* bc, int t) {
  __shared__ float red[NQ][4];
  const int lane = t & 63, w = t >> 6;
#pragma unroll
  for (int q = 0; q < NQ; q++) {
#pragma unroll
    for (int off = 32; off; off >>= 1) v[q] += __shfl_down(v[q], off, 64);
  }
  if (lane == 0) {
#pragma unroll
    for (int q = 0; q < NQ; q++) red[q][w] = v[q];
  }
  __syncthreads();
  if (t < NQ) bc[t] = red[t][0] + red[t][1] + red[t][2] + red[t][3];
  __syncthreads();
}

// ---------------- fp32 -> bf16 convert ----------------
struct ConvArgs { const float* src[6]; u16* dst[6]; };

__global__ __launch_bounds__(256) void convert_bf16(ConvArgs a, int n) {
  const int which = blockIdx.y;
  const float* __restrict__ s = a.src[which];
  u16* __restrict__ d = a.dst[which];
  const int i = (blockIdx.x * 256 + threadIdx.x) * 4;
  if (i >= n) return;
  float4 v = *(const float4*)(s + i);
  uint2 o;
  o.x = (unsigned)f2bf(v.x) | ((unsigned)f2bf(v.y) << 16);
  o.y = (unsigned)f2bf(v.z) | ((unsigned)f2bf(v.w) << 16);
  *(uint2*)(d + i) = o;
}

// ---------------- stage-1 batched bf16 NT GEMM, XCD-swizzled ----------------
// Y = A @ W^T, A[8192][1024], W[1024][1024], both K-major. 128x128 tile.
// Block decode groups all column-blocks sharing an A row-tile onto ONE XCD,
// consecutively, so the A-tile is fetched from HBM once and L2-hit afterwards.
// h feeds gates {0,2}; x feeds gates {1,3,4}.
struct GemmArgs { const u16* A[5]; const u16* Bw[5]; u16* Y[5]; };

__global__ __launch_bounds__(256) void gemm_bt128(GemmArgs args) {
  const int p = blockIdx.x;          // 2560 blocks
  const int xcd = p & 7;
  const int s = p >> 3;              // 0..319 per XCD
  int gate, r, col;
  if (s < 128) {                     // h-group: 8 r x 2 gates x 8 cols
    const int pr = s >> 4;           // 0..7
    const int cc = s & 15;
    gate = (cc >> 3) * 2;            // 0 or 2
    col = cc & 7;
    r = pr * 8 + xcd;                // 0..63
  } else {                           // x-group: 8 r x 3 gates x 8 cols
    const int s2 = s - 128;          // 0..191
    const int pr = s2 / 24;          // 0..7
    const int cc = s2 - pr * 24;     // 0..23
    const int gi = cc >> 3;          // 0,1,2
    gate = (gi == 0) ? 1 : ((gi == 1) ? 3 : 4);
    col = cc & 7;
    r = pr * 8 + xcd;
  }

  const u16* __restrict__ A  = args.A[gate];
  const u16* __restrict__ Bw = args.Bw[gate];
  u16* __restrict__ Y = args.Y[gate];

  __shared__ __attribute__((aligned(16))) u16 As[128 * 32];
  __shared__ __attribute__((aligned(16))) u16 Bs[128 * 32];

  const int tid  = threadIdx.x;
  const int lane = tid & 63;
  const int w    = tid >> 6;
  const int wm   = w >> 1;
  const int wn   = w & 1;

  const int rowBlk = r * 128;
  const int colBlk = col * 128;

  const int lrow = lane >> 2;
  const int lcol = (lane & 3) * 8;
  const int r0a = w * 16;
  const int r0b = 64 + w * 16;

  const u16* gA0 = A  + (size_t)(rowBlk + r0a + lrow) * 1024 + lcol;
  const u16* gA1 = A  + (size_t)(rowBlk + r0b + lrow) * 1024 + lcol;
  const u16* gB0 = Bw + (size_t)(colBlk + r0a + lrow) * 1024 + lcol;
  const u16* gB1 = Bw + (size_t)(colBlk + r0b + lrow) * 1024 + lcol;
  u16* lA0 = &As[r0a * 32];
  u16* lA1 = &As[r0b * 32];
  u16* lB0 = &Bs[r0a * 32];
  u16* lB1 = &Bs[r0b * 32];

  const int aoff = (wm * 64 + (lane & 15)) * 32 + (lane >> 4) * 8;
  const int boff = (wn * 64 + (lane & 15)) * 32 + (lane >> 4) * 8;

  f32x4 acc[4][4] = {};

  for (int k0 = 0; k0 < 1024; k0 += 32) {
    async16(gA0 + k0, lA0);
    async16(gA1 + k0, lA1);
    async16(gB0 + k0, lB0);
    async16(gB1 + k0, lB1);
    __syncthreads();
    bf16x8 af[4], bfr[4];
#pragma unroll
    for (int t = 0; t < 4; t++) {
      af[t]  = *(const bf16x8*)&As[aoff + t * 16 * 32];
      bfr[t] = *(const bf16x8*)&Bs[boff + t * 16 * 32];
    }
#pragma unroll
    for (int tm = 0; tm < 4; tm++)
#pragma unroll
      for (int tn = 0; tn < 4; tn++)
        acc[tm][tn] = __builtin_amdgcn_mfma_f32_16x16x32_bf16(af[tm], bfr[tn], acc[tm][tn], 0, 0, 0);
    __syncthreads();
  }

  const int rBase = rowBlk + wm * 64 + (lane >> 4) * 4;
  const int cBase = colBlk + wn * 64 + (lane & 15);
#pragma unroll
  for (int tm = 0; tm < 4; tm++) {
#pragma unroll
    for (int i = 0; i < 4; i++) {
      const size_t rr = (size_t)(rBase + tm * 16 + i);
#pragma unroll
      for (int tn = 0; tn < 4; tn++)
        Y[rr * 1024 + cBase + tn * 16] = f2bf(acc[tm][tn][i]);
    }
  }
}

// ---------------- stage-2 GEMM: 64x128 tile, 1024 blocks (4/CU) ----------------
__global__ __launch_bounds__(256) void gemm_bt64(const u16* __restrict__ A,
                                                 const u16* __restrict__ Bw,
                                                 u16* __restrict__ Y) {
  const int p = blockIdx.x;          // 1024 blocks
  const int xcd = p & 7;
  const int s = p >> 3;              // 0..127
  const int r = (s >> 3) * 8 + xcd;  // 0..127 (64-row tiles)
  const int col = s & 7;

  __shared__ __attribute__((aligned(16))) u16 As[64 * 32];   // 4 KiB
  __shared__ __attribute__((aligned(16))) u16 Bs[128 * 32];  // 8 KiB

  const int tid  = threadIdx.x;
  const int lane = tid & 63;
  const int w    = tid >> 6;
  const int wm   = w >> 1;   // 0..1: 32-row half
  const int wn   = w & 1;    // 0..1: 64-col half

  const int rowBlk = r * 64;
  const int colBlk = col * 128;

  const int lrow = lane >> 2;
  const int lcol = (lane & 3) * 8;
  const int r0  = w * 16;

  const u16* gA0 = A  + (size_t)(rowBlk + r0 + lrow) * 1024 + lcol;
  const u16* gB0 = Bw + (size_t)(colBlk + r0 + lrow) * 1024 + lcol;
  const u16* gB1 = Bw + (size_t)(colBlk + 64 + r0 + lrow) * 1024 + lcol;
  u16* lA0 = &As[r0 * 32];
  u16* lB0 = &Bs[r0 * 32];
  u16* lB1 = &Bs[(64 + r0) * 32];

  const int aoff = (wm * 32 + (lane & 15)) * 32 + (lane >> 4) * 8;
  const int boff = (wn * 64 + (lane & 15)) * 32 + (lane >> 4) * 8;

  f32x4 acc[2][4] = {};

  for (int k0 = 0; k0 < 1024; k0 += 32) {
    async16(gA0 + k0, lA0);
    async16(gB0 + k0, lB0);
    async16(gB1 + k0, lB1);
    __syncthreads();
    bf16x8 af[2], bfr[4];
#pragma unroll
    for (int t = 0; t < 2; t++) af[t] = *(const bf16x8*)&As[aoff + t * 16 * 32];
#pragma unroll
    for (int t = 0; t < 4; t++) bfr[t] = *(const bf16x8*)&Bs[boff + t * 16 * 32];
#pragma unroll
    for (int tm = 0; tm < 2; tm++)
#pragma unroll
      for (int tn = 0; tn < 4; tn++)
        acc[tm][tn] = __builtin_amdgcn_mfma_f32_16x16x32_bf16(af[tm], bfr[tn], acc[tm][tn], 0, 0, 0);
    __syncthreads();
  }

  const int rBase = rowBlk + wm * 32 + (lane >> 4) * 4;
  const int cBase = colBlk + wn * 64 + (lane & 15);
#pragma unroll
  for (int tm = 0; tm < 2; tm++) {
#pragma unroll
    for (int i = 0; i < 4; i++) {
      const size_t rr = (size_t)(rBase + tm * 16 + i);
#pragma unroll
      for (int tn = 0; tn < 4; tn++)
        Y[rr * 1024 + cBase + tn * 16] = f2bf(acc[tm][tn][i]);
    }
  }
}

// ---------------- stage 2: r = sigmoid(ln(Yrh)+ln(Yrx)); hr = h*r ----------------
__global__ __launch_bounds__(256) void rgate_kernel(
    const u16* __restrict__ Yrh, const u16* __restrict__ Yrx,
    const u16* __restrict__ hb, const float* __restrict__ gamma,
    const float* __restrict__ beta, u16* __restrict__ hrb) {
  const int row = blockIdx.x;
  const int t = threadIdx.x;
  const int c0 = t * 4;
  const size_t base = (size_t)row * 1024 + c0;

  float a[4], b[4], hv[4];
  load4bf(Yrh, base, a);
  load4bf(Yrx, base, b);
  load4bf(hb, base, hv);

  float v[4] = {0.f, 0.f, 0.f, 0.f};
#pragma unroll
  for (int j = 0; j < 4; j++) {
    v[0] += a[j]; v[1] += a[j] * a[j];
    v[2] += b[j]; v[3] += b[j] * b[j];
  }
  __shared__ float bc[4];
  block_reduce_bcast<4>(v, bc, t);

  const float inv = 1.0f / 1024.0f;
  const float mu0 = bc[0] * inv, rs0 = rsqrtf(bc[1] * inv - mu0 * mu0 + 1e-5f);
  const float mu1 = bc[2] * inv, rs1 = rsqrtf(bc[3] * inv - mu1 * mu1 + 1e-5f);

  unsigned pack[2];
#pragma unroll
  for (int j = 0; j < 4; j++) {
    const int c = c0 + j;
    const float ln0 = (a[j] - mu0) * rs0 * gamma[c] + beta[c];
    const float ln1 = (b[j] - mu1) * rs1 * gamma[1024 + c] + beta[1024 + c];
    const float r = fast_sigmoid(ln0 + ln1);
    const float hr = hv[j] * r;
    const unsigned bb = (unsigned)f2bf(hr);
    if (j & 1) pack[j >> 1] |= bb << 16; else pack[j >> 1] = bb;
  }
  uint2 o; o.x = pack[0]; o.y = pack[1];
  *(uint2*)(hrb + base) = o;   // aliases Yrx: per-thread read-before-write
}

// ---------------- stage 4: u, c, out ----------------
__global__ __launch_bounds__(256) void final_fuse(
    const u16* __restrict__ Yuh, const u16* __restrict__ Yux,
    const u16* __restrict__ Ych, const u16* __restrict__ Ycx,
    const u16* __restrict__ hb, const float* __restrict__ gamma,
    const float* __restrict__ beta, float* __restrict__ out) {
  const int row = blockIdx.x;
  const int t = threadIdx.x;
  const int c0 = t * 4;
  const size_t base = (size_t)row * 1024 + c0;

  float a0[4], a1[4], a2[4], a3[4], hv[4];
  load4bf(Yuh, base, a0);
  load4bf(Yux, base, a1);
  load4bf(Ych, base, a2);
  load4bf(Ycx, base, a3);
  load4bf(hb, base, hv);

  float v[8] = {0.f, 0.f, 0.f, 0.f, 0.f, 0.f, 0.f, 0.f};
#pragma unroll
  for (int j = 0; j < 4; j++) {
    v[0] += a0[j]; v[1] += a0[j] * a0[j];
    v[2] += a1[j]; v[3] += a1[j] * a1[j];
    v[4] += a2[j]; v[5] += a2[j] * a2[j];
    v[6] += a3[j]; v[7] += a3[j] * a3[j];
  }
  __shared__ float bc[8];
  block_reduce_bcast<8>(v, bc, t);

  const float inv = 1.0f / 1024.0f;
  const float mu0 = bc[0] * inv, rs0 = rsqrtf(bc[1] * inv - mu0 * mu0 + 1e-5f);
  const float mu1 = bc[2] * inv, rs1 = rsqrtf(bc[3] * inv - mu1 * mu1 + 1e-5f);
  const float mu2 = bc[4] * inv, rs2 = rsqrtf(bc[5] * inv - mu2 * mu2 + 1e-5f);
  const float mu3 = bc[6] * inv, rs3 = rsqrtf(bc[7] * inv - mu3 * mu3 + 1e-5f);

  float o[4];
#pragma unroll
  for (int j = 0; j < 4; j++) {
    const int c = c0 + j;
    const float ln2 = (a0[j] - mu0) * rs0 * gamma[2 * 1024 + c] + beta[2 * 1024 + c];
    const float ln3 = (a1[j] - mu1) * rs1 * gamma[3 * 1024 + c] + beta[3 * 1024 + c];
    const float ln4 = (a2[j] - mu2) * rs2 * gamma[4 * 1024 + c] + beta[4 * 1024 + c];
    const float ln5 = (a3[j] - mu3) * rs3 * gamma[5 * 1024 + c] + beta[5 * 1024 + c];
    const float u = fast_sigmoid(ln2 + ln3);
    const float cg = fast_tanh(ln4 + ln5);
    o[j] = (1.0f - u) * hv[j] + u * cg;
  }
  float4 ov; ov.x = o[0]; ov.y = o[1]; ov.z = o[2]; ov.w = o[3];
  *(float4*)(out + base) = ov;
}

extern "C" void kernel_launch(void* const* d_in, const int* in_sizes, int n_in,
                              void* d_out, int out_size, void* d_ws, size_t ws_size,
                              hipStream_t stream) {
  const float* x  = (const float*)d_in[0];
  const float* h  = (const float*)d_in[1];
  const float* Ws[6] = {(const float*)d_in[2], (const float*)d_in[3],
                        (const float*)d_in[4], (const float*)d_in[5],
                        (const float*)d_in[6], (const float*)d_in[7]};
  const float* gamma = (const float*)d_in[8];
  const float* beta  = (const float*)d_in[9];
  float* out = (float*)d_out;

  char* ws = (char*)d_ws;
  const size_t SZ_ACT = (size_t)8192 * 1024 * 2;  // 16 MiB (bf16)
  const size_t SZ_W   = (size_t)1024 * 1024 * 2;  // 2 MiB

  u16* xb = (u16*)(ws);
  u16* hb = (u16*)(ws + SZ_ACT);
  u16* wb[6];
  for (int i = 0; i < 6; i++) wb[i] = (u16*)(ws + 2 * SZ_ACT + i * SZ_W);
  char* ybase = ws + 2 * SZ_ACT + 6 * SZ_W;
  u16* Y0 = (u16*)(ybase);                 // r_hidden; reused for c_hidden
  u16* Y1 = (u16*)(ybase + SZ_ACT);        // r_input;  reused for hr
  u16* Y2 = (u16*)(ybase + 2 * SZ_ACT);    // u_hidden
  u16* Y3 = (u16*)(ybase + 3 * SZ_ACT);    // u_input
  u16* Y5 = (u16*)(ybase + 4 * SZ_ACT);    // c_input

  // 1) converts
  ConvArgs ca = {};
  ca.src[0] = x; ca.dst[0] = xb;
  ca.src[1] = h; ca.dst[1] = hb;
  convert_bf16<<<dim3(8192, 2), 256, 0, stream>>>(ca, 8192 * 1024);
  ConvArgs cw = {};
  for (int i = 0; i < 6; i++) { cw.src[i] = Ws[i]; cw.dst[i] = wb[i]; }
  convert_bf16<<<dim3(1024, 6), 256, 0, stream>>>(cw, 1024 * 1024);

  // 2) batched stage-1 GEMMs (XCD-swizzled): r_h, r_x, u_h, u_x, c_x
  GemmArgs g = {};
  g.A[0] = hb; g.Bw[0] = wb[0]; g.Y[0] = Y0;   // h @ W_r^T
  g.A[1] = xb; g.Bw[1] = wb[1]; g.Y[1] = Y1;   // x @ U_r^T
  g.A[2] = hb; g.Bw[2] = wb[2]; g.Y[2] = Y2;   // h @ W_u^T
  g.A[3] = xb; g.Bw[3] = wb[3]; g.Y[3] = Y3;   // x @ U_u^T
  g.A[4] = xb; g.Bw[4] = wb[5]; g.Y[4] = Y5;   // x @ U_c^T
  gemm_bt128<<<2560, 256, 0, stream>>>(g);

  // 3) r gate + hr (hr overwrites Y1, safe: per-thread read-before-write)
  rgate_kernel<<<8192, 256, 0, stream>>>(Y0, Y1, hb, gamma, beta, Y1);

  // 4) c_hidden GEMM: hr @ W_c^T -> Y0 (Y0 dead after rgate); 64x128 tiles
  gemm_bt64<<<1024, 256, 0, stream>>>(Y1, wb[4], Y0);

  // 5) u, c, out
  final_fuse<<<8192, 256, 0, stream>>>(Y2, Y3, Y0, Y5, hb, gamma, beta, out);
}

// Round 3
// 308.160 us; speedup vs baseline: 1.2663x; 1.0253x over previous
//
#include <hip/hip_runtime.h>
#include <cstdint>
#include <cstddef>

typedef unsigned short u16;
typedef __attribute__((ext_vector_type(8))) short bf16x8;
typedef __attribute__((ext_vector_type(4))) float f32x4;

__device__ inline float bf2f(u16 u) { return __uint_as_float(((unsigned)u) << 16); }
__device__ inline u16 f2bf(float f) {
  unsigned u = __float_as_uint(f);
  u += 0x7fffu + ((u >> 16) & 1u);   // RNE
  return (u16)(u >> 16);
}

__device__ inline void async16(const u16* g, u16* l) {
  __builtin_amdgcn_global_load_lds(
      (const __attribute__((address_space(1))) void*)g,
      (__attribute__((address_space(3))) void*)l, 16, 0, 0);
}

__device__ inline void unpack8(uint4 q, float* o) {
  o[0] = bf2f((u16)(q.x & 0xffffu)); o[1] = bf2f((u16)(q.x >> 16));
  o[2] = bf2f((u16)(q.y & 0xffffu)); o[3] = bf2f((u16)(q.y >> 16));
  o[4] = bf2f((u16)(q.z & 0xffffu)); o[5] = bf2f((u16)(q.z >> 16));
  o[6] = bf2f((u16)(q.w & 0xffffu)); o[7] = bf2f((u16)(q.w >> 16));
}

__device__ inline uint4 pack8(const float* v) {
  uint4 q;
  q.x = (unsigned)f2bf(v[0]) | ((unsigned)f2bf(v[1]) << 16);
  q.y = (unsigned)f2bf(v[2]) | ((unsigned)f2bf(v[3]) << 16);
  q.z = (unsigned)f2bf(v[4]) | ((unsigned)f2bf(v[5]) << 16);
  q.w = (unsigned)f2bf(v[6]) | ((unsigned)f2bf(v[7]) << 16);
  return q;
}

__device__ inline float fast_sigmoid(float z) {
  return 1.0f / (1.0f + exp2f(-1.4426950408889634f * z));
}
__device__ inline float fast_tanh(float z) {
  return 1.0f - 2.0f / (1.0f + exp2f(2.8853900817779268f * z));
}

// ---------------- fused fp32 -> bf16 convert (x, h, 6 weights in one launch) ----------------
struct ConvAll { const float* src[8]; u16* dst[8]; };

__global__ __launch_bounds__(256) void convert_all(ConvAll a) {
  const int b = blockIdx.x;
  int which, off;
  if (b < 8192)        { which = 0; off = b; }
  else if (b < 16384)  { which = 1; off = b - 8192; }
  else { const int t = b - 16384; which = 2 + (t >> 10); off = t & 1023; }
  const float* __restrict__ s = a.src[which];
  u16* __restrict__ d = a.dst[which];
  const int i = (off * 256 + threadIdx.x) * 4;
  float4 v = *(const float4*)(s + i);
  uint2 o;
  o.x = (unsigned)f2bf(v.x) | ((unsigned)f2bf(v.y) << 16);
  o.y = (unsigned)f2bf(v.z) | ((unsigned)f2bf(v.w) << 16);
  *(uint2*)(d + i) = o;
}

// ---------------- stage-1 batched bf16 NT GEMM, XCD-swizzled (unchanged hot loop) ----------------
struct GemmArgs { const u16* A[5]; const u16* Bw[5]; u16* Y[5]; };

__global__ __launch_bounds__(256) void gemm_bt128(GemmArgs args) {
  const int p = blockIdx.x;          // 2560 blocks
  const int xcd = p & 7;
  const int s = p >> 3;              // 0..319 per XCD
  int gate, r, col;
  if (s < 128) {                     // h-group: 8 r x 2 gates x 8 cols
    const int pr = s >> 4;
    const int cc = s & 15;
    gate = (cc >> 3) * 2;            // 0 or 2
    col = cc & 7;
    r = pr * 8 + xcd;
  } else {                           // x-group: 8 r x 3 gates x 8 cols
    const int s2 = s - 128;
    const int pr = s2 / 24;
    const int cc = s2 - pr * 24;
    const int gi = cc >> 3;
    gate = (gi == 0) ? 1 : ((gi == 1) ? 3 : 4);
    col = cc & 7;
    r = pr * 8 + xcd;
  }

  const u16* __restrict__ A  = args.A[gate];
  const u16* __restrict__ Bw = args.Bw[gate];
  u16* __restrict__ Y = args.Y[gate];

  __shared__ __attribute__((aligned(16))) u16 As[128 * 32];
  __shared__ __attribute__((aligned(16))) u16 Bs[128 * 32];

  const int tid  = threadIdx.x;
  const int lane = tid & 63;
  const int w    = tid >> 6;
  const int wm   = w >> 1;
  const int wn   = w & 1;

  const int rowBlk = r * 128;
  const int colBlk = col * 128;

  const int lrow = lane >> 2;
  const int lcol = (lane & 3) * 8;
  const int r0a = w * 16;
  const int r0b = 64 + w * 16;

  const u16* gA0 = A  + (size_t)(rowBlk + r0a + lrow) * 1024 + lcol;
  const u16* gA1 = A  + (size_t)(rowBlk + r0b + lrow) * 1024 + lcol;
  const u16* gB0 = Bw + (size_t)(colBlk + r0a + lrow) * 1024 + lcol;
  const u16* gB1 = Bw + (size_t)(colBlk + r0b + lrow) * 1024 + lcol;
  u16* lA0 = &As[r0a * 32];
  u16* lA1 = &As[r0b * 32];
  u16* lB0 = &Bs[r0a * 32];
  u16* lB1 = &Bs[r0b * 32];

  const int aoff = (wm * 64 + (lane & 15)) * 32 + (lane >> 4) * 8;
  const int boff = (wn * 64 + (lane & 15)) * 32 + (lane >> 4) * 8;

  f32x4 acc[4][4] = {};

  for (int k0 = 0; k0 < 1024; k0 += 32) {
    async16(gA0 + k0, lA0);
    async16(gA1 + k0, lA1);
    async16(gB0 + k0, lB0);
    async16(gB1 + k0, lB1);
    __syncthreads();
    bf16x8 af[4], bfr[4];
#pragma unroll
    for (int t = 0; t < 4; t++) {
      af[t]  = *(const bf16x8*)&As[aoff + t * 16 * 32];
      bfr[t] = *(const bf16x8*)&Bs[boff + t * 16 * 32];
    }
#pragma unroll
    for (int tm = 0; tm < 4; tm++)
#pragma unroll
      for (int tn = 0; tn < 4; tn++)
        acc[tm][tn] = __builtin_amdgcn_mfma_f32_16x16x32_bf16(af[tm], bfr[tn], acc[tm][tn], 0, 0, 0);
    __syncthreads();
  }

  const int rBase = rowBlk + wm * 64 + (lane >> 4) * 4;
  const int cBase = colBlk + wn * 64 + (lane & 15);
#pragma unroll
  for (int tm = 0; tm < 4; tm++) {
#pragma unroll
    for (int i = 0; i < 4; i++) {
      const size_t rr = (size_t)(rBase + tm * 16 + i);
#pragma unroll
      for (int tn = 0; tn < 4; tn++)
        Y[rr * 1024 + cBase + tn * 16] = f2bf(acc[tm][tn][i]);
    }
  }
}

// ---------------- stage-2 GEMM: 8 waves, 128x128 tile, 512 blocks, XCD-swizzled ----------------
__global__ __launch_bounds__(512) void gemm_hr(const u16* __restrict__ A,
                                               const u16* __restrict__ Bw,
                                               u16* __restrict__ Y) {
  const int p = blockIdx.x;          // 512 blocks
  const int xcd = p & 7;
  const int s = p >> 3;              // 0..63
  const int col = s & 7;
  const int r = (s >> 3) * 8 + xcd;  // 0..63

  __shared__ __attribute__((aligned(16))) u16 As[128 * 32];
  __shared__ __attribute__((aligned(16))) u16 Bs[128 * 32];

  const int tid  = threadIdx.x;
  const int lane = tid & 63;
  const int w    = tid >> 6;   // 0..7
  const int wm   = w >> 2;     // 0..1 : 64-row half
  const int wn   = w & 3;      // 0..3 : 32-col quarter

  const int rowBlk = r * 128;
  const int colBlk = col * 128;

  const int lrow = lane >> 2;
  const int lcol = (lane & 3) * 8;
  const int r0 = w * 16;       // each wave stages 16 rows of A and 16 of B

  const u16* gA = A  + (size_t)(rowBlk + r0 + lrow) * 1024 + lcol;
  const u16* gB = Bw + (size_t)(colBlk + r0 + lrow) * 1024 + lcol;
  u16* lA = &As[r0 * 32];
  u16* lB = &Bs[r0 * 32];

  const int aoff = (wm * 64 + (lane & 15)) * 32 + (lane >> 4) * 8;
  const int boff = (wn * 32 + (lane & 15)) * 32 + (lane >> 4) * 8;

  f32x4 acc[4][2] = {};

  for (int k0 = 0; k0 < 1024; k0 += 32) {
    async16(gA + k0, lA);
    async16(gB + k0, lB);
    __syncthreads();
    bf16x8 af[4], bfr[2];
#pragma unroll
    for (int t = 0; t < 4; t++) af[t]  = *(const bf16x8*)&As[aoff + t * 16 * 32];
#pragma unroll
    for (int t = 0; t < 2; t++) bfr[t] = *(const bf16x8*)&Bs[boff + t * 16 * 32];
#pragma unroll
    for (int tm = 0; tm < 4; tm++)
#pragma unroll
      for (int tn = 0; tn < 2; tn++)
        acc[tm][tn] = __builtin_amdgcn_mfma_f32_16x16x32_bf16(af[tm], bfr[tn], acc[tm][tn], 0, 0, 0);
    __syncthreads();
  }

  const int rBase = rowBlk + wm * 64 + (lane >> 4) * 4;
  const int cBase = colBlk + wn * 32 + (lane & 15);
#pragma unroll
  for (int tm = 0; tm < 4; tm++) {
#pragma unroll
    for (int i = 0; i < 4; i++) {
      const size_t rr = (size_t)(rBase + tm * 16 + i);
#pragma unroll
      for (int tn = 0; tn < 2; tn++)
        Y[rr * 1024 + cBase + tn * 16] = f2bf(acc[tm][tn][i]);
    }
  }
}

// ---------------- r gate: wave-per-row, no barriers ----------------
__global__ __launch_bounds__(256) void rgate_kernel(
    const u16* __restrict__ Yrh, const u16* __restrict__ Yrx,
    const u16* __restrict__ hb, const float* __restrict__ gamma,
    const float* __restrict__ beta, u16* __restrict__ hrb) {
  const int row  = blockIdx.x * 4 + (threadIdx.x >> 6);
  const int lane = threadIdx.x & 63;
  const size_t rb = (size_t)row * 1024;

  uint4 qa[2], qb[2], qh[2];
  qa[0] = *(const uint4*)(Yrh + rb + lane * 8);
  qa[1] = *(const uint4*)(Yrh + rb + 512 + lane * 8);
  qb[0] = *(const uint4*)(Yrx + rb + lane * 8);
  qb[1] = *(const uint4*)(Yrx + rb + 512 + lane * 8);
  qh[0] = *(const uint4*)(hb  + rb + lane * 8);
  qh[1] = *(const uint4*)(hb  + rb + 512 + lane * 8);

  float s0 = 0.f, s0q = 0.f, s1 = 0.f, s1q = 0.f;
  float tmp[8];
#pragma unroll
  for (int c = 0; c < 2; c++) {
    unpack8(qa[c], tmp);
#pragma unroll
    for (int j = 0; j < 8; j++) { s0 += tmp[j]; s0q += tmp[j] * tmp[j]; }
    unpack8(qb[c], tmp);
#pragma unroll
    for (int j = 0; j < 8; j++) { s1 += tmp[j]; s1q += tmp[j] * tmp[j]; }
  }
#pragma unroll
  for (int off = 1; off < 64; off <<= 1) {
    s0 += __shfl_xor(s0, off, 64);  s0q += __shfl_xor(s0q, off, 64);
    s1 += __shfl_xor(s1, off, 64);  s1q += __shfl_xor(s1q, off, 64);
  }

  const float inv = 1.0f / 1024.0f;
  const float mu0 = s0 * inv, rs0 = rsqrtf(s0q * inv - mu0 * mu0 + 1e-5f);
  const float mu1 = s1 * inv, rs1 = rsqrtf(s1q * inv - mu1 * mu1 + 1e-5f);

#pragma unroll
  for (int c = 0; c < 2; c++) {
    const int cb = c * 512 + lane * 8;
    float va[8], vb[8], vh[8], o[8];
    unpack8(qa[c], va); unpack8(qb[c], vb); unpack8(qh[c], vh);
#pragma unroll
    for (int j = 0; j < 8; j++) {
      const float ln0 = (va[j] - mu0) * rs0 * gamma[cb + j] + beta[cb + j];
      const float ln1 = (vb[j] - mu1) * rs1 * gamma[1024 + cb + j] + beta[1024 + cb + j];
      const float rg = fast_sigmoid(ln0 + ln1);
      o[j] = vh[j] * rg;
    }
    *(uint4*)(hrb + rb + cb) = pack8(o);  // aliases Yrx: per-thread read-before-write
  }
}

// ---------------- final: wave-per-row, no barriers ----------------
__global__ __launch_bounds__(256) void final_fuse(
    const u16* __restrict__ Yuh, const u16* __restrict__ Yux,
    const u16* __restrict__ Ych, const u16* __restrict__ Ycx,
    const u16* __restrict__ hb, const float* __restrict__ gamma,
    const float* __restrict__ beta, float* __restrict__ out) {
  const int row  = blockIdx.x * 4 + (threadIdx.x >> 6);
  const int lane = threadIdx.x & 63;
  const size_t rb = (size_t)row * 1024;

  uint4 q0[2], q1[2], q2[2], q3[2], qh[2];
#pragma unroll
  for (int c = 0; c < 2; c++) {
    const int cb = c * 512 + lane * 8;
    q0[c] = *(const uint4*)(Yuh + rb + cb);
    q1[c] = *(const uint4*)(Yux + rb + cb);
    q2[c] = *(const uint4*)(Ych + rb + cb);
    q3[c] = *(const uint4*)(Ycx + rb + cb);
    qh[c] = *(const uint4*)(hb  + rb + cb);
  }

  float s[8] = {0.f, 0.f, 0.f, 0.f, 0.f, 0.f, 0.f, 0.f};
  float tmp[8];
#pragma unroll
  for (int c = 0; c < 2; c++) {
    unpack8(q0[c], tmp);
#pragma unroll
    for (int j = 0; j < 8; j++) { s[0] += tmp[j]; s[1] += tmp[j] * tmp[j]; }
    unpack8(q1[c], tmp);
#pragma unroll
    for (int j = 0; j < 8; j++) { s[2] += tmp[j]; s[3] += tmp[j] * tmp[j]; }
    unpack8(q2[c], tmp);
#pragma unroll
    for (int j = 0; j < 8; j++) { s[4] += tmp[j]; s[5] += tmp[j] * tmp[j]; }
    unpack8(q3[c], tmp);
#pragma unroll
    for (int j = 0; j < 8; j++) { s[6] += tmp[j]; s[7] += tmp[j] * tmp[j]; }
  }
#pragma unroll
  for (int off = 1; off < 64; off <<= 1) {
#pragma unroll
    for (int q = 0; q < 8; q++) s[q] += __shfl_xor(s[q], off, 64);
  }

  const float inv = 1.0f / 1024.0f;
  const float mu0 = s[0] * inv, rs0 = rsqrtf(s[1] * inv - mu0 * mu0 + 1e-5f);
  const float mu1 = s[2] * inv, rs1 = rsqrtf(s[3] * inv - mu1 * mu1 + 1e-5f);
  const float mu2 = s[4] * inv, rs2 = rsqrtf(s[5] * inv - mu2 * mu2 + 1e-5f);
  const float mu3 = s[6] * inv, rs3 = rsqrtf(s[7] * inv - mu3 * mu3 + 1e-5f);

#pragma unroll
  for (int c = 0; c < 2; c++) {
    const int cb = c * 512 + lane * 8;
    float v0[8], v1[8], v2[8], v3[8], vh[8];
    unpack8(q0[c], v0); unpack8(q1[c], v1); unpack8(q2[c], v2);
    unpack8(q3[c], v3); unpack8(qh[c], vh);
    float o[8];
#pragma unroll
    for (int j = 0; j < 8; j++) {
      const int cc = cb + j;
      const float ln2 = (v0[j] - mu0) * rs0 * gamma[2 * 1024 + cc] + beta[2 * 1024 + cc];
      const float ln3 = (v1[j] - mu1) * rs1 * gamma[3 * 1024 + cc] + beta[3 * 1024 + cc];
      const float ln4 = (v2[j] - mu2) * rs2 * gamma[4 * 1024 + cc] + beta[4 * 1024 + cc];
      const float ln5 = (v3[j] - mu3) * rs3 * gamma[5 * 1024 + cc] + beta[5 * 1024 + cc];
      const float u  = fast_sigmoid(ln2 + ln3);
      const float cg = fast_tanh(ln4 + ln5);
      o[j] = (1.0f - u) * vh[j] + u * cg;
    }
    *(float4*)(out + rb + cb)     = *(float4*)&o[0];
    *(float4*)(out + rb + cb + 4) = *(float4*)&o[4];
  }
}

extern "C" void kernel_launch(void* const* d_in, const int* in_sizes, int n_in,
                              void* d_out, int out_size, void* d_ws, size_t ws_size,
                              hipStream_t stream) {
  const float* x  = (const float*)d_in[0];
  const float* h  = (const float*)d_in[1];
  const float* Ws[6] = {(const float*)d_in[2], (const float*)d_in[3],
                        (const float*)d_in[4], (const float*)d_in[5],
                        (const float*)d_in[6], (const float*)d_in[7]};
  const float* gamma = (const float*)d_in[8];
  const float* beta  = (const float*)d_in[9];
  float* out = (float*)d_out;

  char* ws = (char*)d_ws;
  const size_t SZ_ACT = (size_t)8192 * 1024 * 2;  // 16 MiB (bf16)
  const size_t SZ_W   = (size_t)1024 * 1024 * 2;  // 2 MiB

  u16* xb = (u16*)(ws);
  u16* hb = (u16*)(ws + SZ_ACT);
  u16* wb[6];
  for (int i = 0; i < 6; i++) wb[i] = (u16*)(ws + 2 * SZ_ACT + i * SZ_W);
  char* ybase = ws + 2 * SZ_ACT + 6 * SZ_W;
  u16* Y0 = (u16*)(ybase);                 // r_hidden; reused for c_hidden
  u16* Y1 = (u16*)(ybase + SZ_ACT);        // r_input;  reused for hr
  u16* Y2 = (u16*)(ybase + 2 * SZ_ACT);    // u_hidden
  u16* Y3 = (u16*)(ybase + 3 * SZ_ACT);    // u_input
  u16* Y5 = (u16*)(ybase + 4 * SZ_ACT);    // c_input

  // 1) one fused convert launch: x (8192 blk), h (8192 blk), 6 weights (1024 blk each)
  ConvAll ca = {};
  ca.src[0] = x; ca.dst[0] = xb;
  ca.src[1] = h; ca.dst[1] = hb;
  for (int i = 0; i < 6; i++) { ca.src[2 + i] = Ws[i]; ca.dst[2 + i] = wb[i]; }
  convert_all<<<16384 + 6 * 1024, 256, 0, stream>>>(ca);

  // 2) batched stage-1 GEMMs (XCD-swizzled): r_h, r_x, u_h, u_x, c_x
  GemmArgs g = {};
  g.A[0] = hb; g.Bw[0] = wb[0]; g.Y[0] = Y0;   // h @ W_r^T
  g.A[1] = xb; g.Bw[1] = wb[1]; g.Y[1] = Y1;   // x @ U_r^T
  g.A[2] = hb; g.Bw[2] = wb[2]; g.Y[2] = Y2;   // h @ W_u^T
  g.A[3] = xb; g.Bw[3] = wb[3]; g.Y[3] = Y3;   // x @ U_u^T
  g.A[4] = xb; g.Bw[4] = wb[5]; g.Y[4] = Y5;   // x @ U_c^T
  gemm_bt128<<<2560, 256, 0, stream>>>(g);

  // 3) r gate + hr (hr overwrites Y1; per-thread read-before-write)
  rgate_kernel<<<2048, 256, 0, stream>>>(Y0, Y1, hb, gamma, beta, Y1);

  // 4) c_hidden GEMM: hr @ W_c^T -> Y0 (Y0 dead after rgate)
  gemm_hr<<<512, 512, 0, stream>>>(Y1, wb[4], Y0);

  // 5) u, c, out
  final_fuse<<<2048, 256, 0, stream>>>(Y2, Y3, Y0, Y5, hb, gamma, beta, out);
}

// Round 4
// 296.329 us; speedup vs baseline: 1.3169x; 1.0399x over previous
//
#include <hip/hip_runtime.h>
#include <cstdint>
#include <cstddef>

typedef unsigned short u16;
typedef __attribute__((ext_vector_type(8))) short bf16x8;
typedef __attribute__((ext_vector_type(4))) float f32x4;

__device__ inline float bf2f(u16 u) { return __uint_as_float(((unsigned)u) << 16); }
__device__ inline u16 f2bf(float f) {
  unsigned u = __float_as_uint(f);
  u += 0x7fffu + ((u >> 16) & 1u);   // RNE
  return (u16)(u >> 16);
}

__device__ inline void async16(const u16* g, u16* l) {
  __builtin_amdgcn_global_load_lds(
      (const __attribute__((address_space(1))) void*)g,
      (__attribute__((address_space(3))) void*)l, 16, 0, 0);
}

__device__ inline void unpack8(uint4 q, float* o) {
  o[0] = bf2f((u16)(q.x & 0xffffu)); o[1] = bf2f((u16)(q.x >> 16));
  o[2] = bf2f((u16)(q.y & 0xffffu)); o[3] = bf2f((u16)(q.y >> 16));
  o[4] = bf2f((u16)(q.z & 0xffffu)); o[5] = bf2f((u16)(q.z >> 16));
  o[6] = bf2f((u16)(q.w & 0xffffu)); o[7] = bf2f((u16)(q.w >> 16));
}

__device__ inline uint4 pack8(const float* v) {
  uint4 q;
  q.x = (unsigned)f2bf(v[0]) | ((unsigned)f2bf(v[1]) << 16);
  q.y = (unsigned)f2bf(v[2]) | ((unsigned)f2bf(v[3]) << 16);
  q.z = (unsigned)f2bf(v[4]) | ((unsigned)f2bf(v[5]) << 16);
  q.w = (unsigned)f2bf(v[6]) | ((unsigned)f2bf(v[7]) << 16);
  return q;
}

__device__ inline float fast_sigmoid(float z) {
  return 1.0f / (1.0f + exp2f(-1.4426950408889634f * z));
}
__device__ inline float fast_tanh(float z) {
  return 1.0f - 2.0f / (1.0f + exp2f(2.8853900817779268f * z));
}

// ---------------- fused fp32 -> bf16 convert ----------------
struct ConvAll { const float* src[8]; u16* dst[8]; };

__global__ __launch_bounds__(256) void convert_all(ConvAll a) {
  const int b = blockIdx.x;
  int which, off;
  if (b < 8192)        { which = 0; off = b; }
  else if (b < 16384)  { which = 1; off = b - 8192; }
  else { const int t = b - 16384; which = 2 + (t >> 10); off = t & 1023; }
  const float* __restrict__ s = a.src[which];
  u16* __restrict__ d = a.dst[which];
  const int i = (off * 256 + threadIdx.x) * 4;
  float4 v = *(const float4*)(s + i);
  uint2 o;
  o.x = (unsigned)f2bf(v.x) | ((unsigned)f2bf(v.y) << 16);
  o.y = (unsigned)f2bf(v.z) | ((unsigned)f2bf(v.w) << 16);
  *(uint2*)(d + i) = o;
}

// ---------------- stage-1 batched NT GEMM: 128x128 tile, BK=64, XOR-swizzled LDS ----------------
// LDS layout: row-major [128][64] u16 (128 B/row = 8 groups of 16 B).
// Physical group p of row r holds logical k-group p ^ (r & 7)  (conflict-free b128 reads).
// global_load_lds writes base + lane*16: lane l -> (row = chunk + l>>3, p = l&7),
// so the GLOBAL column is permuted per lane: logical group = (l&7) ^ (l>>3).
struct GemmArgs { const u16* A[5]; const u16* Bw[5]; u16* Y[5]; };

__global__ __launch_bounds__(256) void gemm_bt128(GemmArgs args) {
  const int p = blockIdx.x;          // 2560 blocks
  const int xcd = p & 7;
  const int s = p >> 3;
  int gate, r, col;
  if (s < 128) {                     // h-group: 8 r x 2 gates x 8 cols
    const int pr = s >> 4;
    const int cc = s & 15;
    gate = (cc >> 3) * 2;            // 0 or 2
    col = cc & 7;
    r = pr * 8 + xcd;
  } else {                           // x-group: 8 r x 3 gates x 8 cols
    const int s2 = s - 128;
    const int pr = s2 / 24;
    const int cc = s2 - pr * 24;
    const int gi = cc >> 3;
    gate = (gi == 0) ? 1 : ((gi == 1) ? 3 : 4);
    col = cc & 7;
    r = pr * 8 + xcd;
  }

  const u16* __restrict__ A  = args.A[gate];
  const u16* __restrict__ Bw = args.Bw[gate];
  u16* __restrict__ Y = args.Y[gate];

  __shared__ __attribute__((aligned(16))) u16 As[128 * 64];  // 16 KiB
  __shared__ __attribute__((aligned(16))) u16 Bs[128 * 64];  // 16 KiB

  const int tid  = threadIdx.x;
  const int lane = tid & 63;
  const int w    = tid >> 6;
  const int wm   = w >> 1;
  const int wn   = w & 1;

  const int rowBlk = r * 128;
  const int colBlk = col * 128;

  // staging: 4 chunks of 8 rows per wave; lane l -> row chunk+(l>>3), global col ((l&7)^(l>>3))*8
  const int srow = lane >> 3;
  const int scol = ((lane & 7) ^ srow) * 8;
  const u16* gA[4]; const u16* gB[4]; u16* lA[4]; u16* lB[4];
#pragma unroll
  for (int i = 0; i < 4; i++) {
    const int rr = w * 32 + i * 8;
    gA[i] = A  + (size_t)(rowBlk + rr + srow) * 1024 + scol;
    gB[i] = Bw + (size_t)(colBlk + rr + srow) * 1024 + scol;
    lA[i] = &As[rr * 64];
    lB[i] = &Bs[rr * 64];
  }

  // fragment bases: row = (lane&15) (+ t*16), row&7 == lane&7 for all t
  const int swz = (((lane >> 4) ^ (lane & 7)) << 3);
  const int fa = (wm * 64 + (lane & 15)) * 64 + swz;
  const int fb = (wn * 64 + (lane & 15)) * 64 + swz;

  f32x4 acc[4][4] = {};

  for (int k0 = 0; k0 < 1024; k0 += 64) {
#pragma unroll
    for (int i = 0; i < 4; i++) {
      async16(gA[i] + k0, lA[i]);
      async16(gB[i] + k0, lB[i]);
    }
    __syncthreads();
#pragma unroll
    for (int kk = 0; kk < 2; kk++) {
      const int kx = kk << 5;   // flips bit 5 of the group field (4*16B in elements)
      bf16x8 af[4], bfr[4];
#pragma unroll
      for (int t = 0; t < 4; t++) {
        af[t]  = *(const bf16x8*)&As[(fa + t * 1024) ^ kx];
        bfr[t] = *(const bf16x8*)&Bs[(fb + t * 1024) ^ kx];
      }
#pragma unroll
      for (int tm = 0; tm < 4; tm++)
#pragma unroll
        for (int tn = 0; tn < 4; tn++)
          acc[tm][tn] = __builtin_amdgcn_mfma_f32_16x16x32_bf16(af[tm], bfr[tn], acc[tm][tn], 0, 0, 0);
    }
    __syncthreads();
  }

  const int rBase = rowBlk + wm * 64 + (lane >> 4) * 4;
  const int cBase = colBlk + wn * 64 + (lane & 15);
#pragma unroll
  for (int tm = 0; tm < 4; tm++) {
#pragma unroll
    for (int i = 0; i < 4; i++) {
      const size_t rr = (size_t)(rBase + tm * 16 + i);
#pragma unroll
      for (int tn = 0; tn < 4; tn++)
        Y[rr * 1024 + cBase + tn * 16] = f2bf(acc[tm][tn][i]);
    }
  }
}

// ---------------- stage-2 GEMM: 64x128 tile, BK=64, swizzled, 1024 blocks ----------------
__global__ __launch_bounds__(256) void gemm_hr(const u16* __restrict__ A,
                                               const u16* __restrict__ Bw,
                                               u16* __restrict__ Y) {
  const int p = blockIdx.x;          // 1024 blocks
  const int xcd = p & 7;
  const int s = p >> 3;              // 0..127
  const int col = s & 7;
  const int r = (s >> 3) * 8 + xcd;  // 0..127

  __shared__ __attribute__((aligned(16))) u16 As[64 * 64];    // 8 KiB
  __shared__ __attribute__((aligned(16))) u16 Bs[128 * 64];   // 16 KiB

  const int tid  = threadIdx.x;
  const int lane = tid & 63;
  const int w    = tid >> 6;   // 0..3
  const int wm   = w >> 1;     // 0..1 : 32-row half
  const int wn   = w & 1;      // 0..1 : 64-col half

  const int rowBlk = r * 64;
  const int colBlk = col * 128;

  const int srow = lane >> 3;
  const int scol = ((lane & 7) ^ srow) * 8;
  const u16* gA[2]; u16* lA[2];
  const u16* gB[4]; u16* lB[4];
#pragma unroll
  for (int i = 0; i < 2; i++) {
    const int rr = w * 16 + i * 8;
    gA[i] = A + (size_t)(rowBlk + rr + srow) * 1024 + scol;
    lA[i] = &As[rr * 64];
  }
#pragma unroll
  for (int i = 0; i < 4; i++) {
    const int rr = w * 32 + i * 8;
    gB[i] = Bw + (size_t)(colBlk + rr + srow) * 1024 + scol;
    lB[i] = &Bs[rr * 64];
  }

  const int swz = (((lane >> 4) ^ (lane & 7)) << 3);
  const int fa = (wm * 32 + (lane & 15)) * 64 + swz;
  const int fb = (wn * 64 + (lane & 15)) * 64 + swz;

  f32x4 acc[2][4] = {};

  for (int k0 = 0; k0 < 1024; k0 += 64) {
#pragma unroll
    for (int i = 0; i < 2; i++) async16(gA[i] + k0, lA[i]);
#pragma unroll
    for (int i = 0; i < 4; i++) async16(gB[i] + k0, lB[i]);
    __syncthreads();
#pragma unroll
    for (int kk = 0; kk < 2; kk++) {
      const int kx = kk << 5;
      bf16x8 af[2], bfr[4];
#pragma unroll
      for (int t = 0; t < 2; t++) af[t]  = *(const bf16x8*)&As[(fa + t * 1024) ^ kx];
#pragma unroll
      for (int t = 0; t < 4; t++) bfr[t] = *(const bf16x8*)&Bs[(fb + t * 1024) ^ kx];
#pragma unroll
      for (int tm = 0; tm < 2; tm++)
#pragma unroll
        for (int tn = 0; tn < 4; tn++)
          acc[tm][tn] = __builtin_amdgcn_mfma_f32_16x16x32_bf16(af[tm], bfr[tn], acc[tm][tn], 0, 0, 0);
    }
    __syncthreads();
  }

  const int rBase = rowBlk + wm * 32 + (lane >> 4) * 4;
  const int cBase = colBlk + wn * 64 + (lane & 15);
#pragma unroll
  for (int tm = 0; tm < 2; tm++) {
#pragma unroll
    for (int i = 0; i < 4; i++) {
      const size_t rr = (size_t)(rBase + tm * 16 + i);
#pragma unroll
      for (int tn = 0; tn < 4; tn++)
        Y[rr * 1024 + cBase + tn * 16] = f2bf(acc[tm][tn][i]);
    }
  }
}

// ---------------- r gate: wave-per-row, no barriers ----------------
__global__ __launch_bounds__(256) void rgate_kernel(
    const u16* __restrict__ Yrh, const u16* __restrict__ Yrx,
    const u16* __restrict__ hb, const float* __restrict__ gamma,
    const float* __restrict__ beta, u16* __restrict__ hrb) {
  const int row  = blockIdx.x * 4 + (threadIdx.x >> 6);
  const int lane = threadIdx.x & 63;
  const size_t rb = (size_t)row * 1024;

  uint4 qa[2], qb[2], qh[2];
  qa[0] = *(const uint4*)(Yrh + rb + lane * 8);
  qa[1] = *(const uint4*)(Yrh + rb + 512 + lane * 8);
  qb[0] = *(const uint4*)(Yrx + rb + lane * 8);
  qb[1] = *(const uint4*)(Yrx + rb + 512 + lane * 8);
  qh[0] = *(const uint4*)(hb  + rb + lane * 8);
  qh[1] = *(const uint4*)(hb  + rb + 512 + lane * 8);

  float s0 = 0.f, s0q = 0.f, s1 = 0.f, s1q = 0.f;
  float tmp[8];
#pragma unroll
  for (int c = 0; c < 2; c++) {
    unpack8(qa[c], tmp);
#pragma unroll
    for (int j = 0; j < 8; j++) { s0 += tmp[j]; s0q += tmp[j] * tmp[j]; }
    unpack8(qb[c], tmp);
#pragma unroll
    for (int j = 0; j < 8; j++) { s1 += tmp[j]; s1q += tmp[j] * tmp[j]; }
  }
#pragma unroll
  for (int off = 1; off < 64; off <<= 1) {
    s0 += __shfl_xor(s0, off, 64);  s0q += __shfl_xor(s0q, off, 64);
    s1 += __shfl_xor(s1, off, 64);  s1q += __shfl_xor(s1q, off, 64);
  }

  const float inv = 1.0f / 1024.0f;
  const float mu0 = s0 * inv, rs0 = rsqrtf(s0q * inv - mu0 * mu0 + 1e-5f);
  const float mu1 = s1 * inv, rs1 = rsqrtf(s1q * inv - mu1 * mu1 + 1e-5f);

#pragma unroll
  for (int c = 0; c < 2; c++) {
    const int cb = c * 512 + lane * 8;
    float va[8], vb[8], vh[8], o[8];
    unpack8(qa[c], va); unpack8(qb[c], vb); unpack8(qh[c], vh);
#pragma unroll
    for (int j = 0; j < 8; j++) {
      const float ln0 = (va[j] - mu0) * rs0 * gamma[cb + j] + beta[cb + j];
      const float ln1 = (vb[j] - mu1) * rs1 * gamma[1024 + cb + j] + beta[1024 + cb + j];
      const float rg = fast_sigmoid(ln0 + ln1);
      o[j] = vh[j] * rg;
    }
    *(uint4*)(hrb + rb + cb) = pack8(o);  // aliases Yrx: per-thread read-before-write
  }
}

// ---------------- final: wave-per-row, h read in fp32 for accuracy ----------------
__global__ __launch_bounds__(256) void final_fuse(
    const u16* __restrict__ Yuh, const u16* __restrict__ Yux,
    const u16* __restrict__ Ych, const u16* __restrict__ Ycx,
    const float* __restrict__ h, const float* __restrict__ gamma,
    const float* __restrict__ beta, float* __restrict__ out) {
  const int row  = blockIdx.x * 4 + (threadIdx.x >> 6);
  const int lane = threadIdx.x & 63;
  const size_t rb = (size_t)row * 1024;

  uint4 q0[2], q1[2], q2[2], q3[2];
  float4 hf[4];
#pragma unroll
  for (int c = 0; c < 2; c++) {
    const int cb = c * 512 + lane * 8;
    q0[c] = *(const uint4*)(Yuh + rb + cb);
    q1[c] = *(const uint4*)(Yux + rb + cb);
    q2[c] = *(const uint4*)(Ych + rb + cb);
    q3[c] = *(const uint4*)(Ycx + rb + cb);
    hf[c * 2]     = *(const float4*)(h + rb + cb);
    hf[c * 2 + 1] = *(const float4*)(h + rb + cb + 4);
  }

  float s[8] = {0.f, 0.f, 0.f, 0.f, 0.f, 0.f, 0.f, 0.f};
  float tmp[8];
#pragma unroll
  for (int c = 0; c < 2; c++) {
    unpack8(q0[c], tmp);
#pragma unroll
    for (int j = 0; j < 8; j++) { s[0] += tmp[j]; s[1] += tmp[j] * tmp[j]; }
    unpack8(q1[c], tmp);
#pragma unroll
    for (int j = 0; j < 8; j++) { s[2] += tmp[j]; s[3] += tmp[j] * tmp[j]; }
    unpack8(q2[c], tmp);
#pragma unroll
    for (int j = 0; j < 8; j++) { s[4] += tmp[j]; s[5] += tmp[j] * tmp[j]; }
    unpack8(q3[c], tmp);
#pragma unroll
    for (int j = 0; j < 8; j++) { s[6] += tmp[j]; s[7] += tmp[j] * tmp[j]; }
  }
#pragma unroll
  for (int off = 1; off < 64; off <<= 1) {
#pragma unroll
    for (int q = 0; q < 8; q++) s[q] += __shfl_xor(s[q], off, 64);
  }

  const float inv = 1.0f / 1024.0f;
  const float mu0 = s[0] * inv, rs0 = rsqrtf(s[1] * inv - mu0 * mu0 + 1e-5f);
  const float mu1 = s[2] * inv, rs1 = rsqrtf(s[3] * inv - mu1 * mu1 + 1e-5f);
  const float mu2 = s[4] * inv, rs2 = rsqrtf(s[5] * inv - mu2 * mu2 + 1e-5f);
  const float mu3 = s[6] * inv, rs3 = rsqrtf(s[7] * inv - mu3 * mu3 + 1e-5f);

#pragma unroll
  for (int c = 0; c < 2; c++) {
    const int cb = c * 512 + lane * 8;
    float v0[8], v1[8], v2[8], v3[8];
    unpack8(q0[c], v0); unpack8(q1[c], v1); unpack8(q2[c], v2); unpack8(q3[c], v3);
    const float* hv = (const float*)&hf[c * 2];
    float o[8];
#pragma unroll
    for (int j = 0; j < 8; j++) {
      const int cc = cb + j;
      const float ln2 = (v0[j] - mu0) * rs0 * gamma[2 * 1024 + cc] + beta[2 * 1024 + cc];
      const float ln3 = (v1[j] - mu1) * rs1 * gamma[3 * 1024 + cc] + beta[3 * 1024 + cc];
      const float ln4 = (v2[j] - mu2) * rs2 * gamma[4 * 1024 + cc] + beta[4 * 1024 + cc];
      const float ln5 = (v3[j] - mu3) * rs3 * gamma[5 * 1024 + cc] + beta[5 * 1024 + cc];
      const float u  = fast_sigmoid(ln2 + ln3);
      const float cg = fast_tanh(ln4 + ln5);
      o[j] = (1.0f - u) * hv[j] + u * cg;
    }
    *(float4*)(out + rb + cb)     = *(float4*)&o[0];
    *(float4*)(out + rb + cb + 4) = *(float4*)&o[4];
  }
}

extern "C" void kernel_launch(void* const* d_in, const int* in_sizes, int n_in,
                              void* d_out, int out_size, void* d_ws, size_t ws_size,
                              hipStream_t stream) {
  const float* x  = (const float*)d_in[0];
  const float* h  = (const float*)d_in[1];
  const float* Ws[6] = {(const float*)d_in[2], (const float*)d_in[3],
                        (const float*)d_in[4], (const float*)d_in[5],
                        (const float*)d_in[6], (const float*)d_in[7]};
  const float* gamma = (const float*)d_in[8];
  const float* beta  = (const float*)d_in[9];
  float* out = (float*)d_out;

  char* ws = (char*)d_ws;
  const size_t SZ_ACT = (size_t)8192 * 1024 * 2;  // 16 MiB (bf16)
  const size_t SZ_W   = (size_t)1024 * 1024 * 2;  // 2 MiB

  u16* xb = (u16*)(ws);
  u16* hb = (u16*)(ws + SZ_ACT);
  u16* wb[6];
  for (int i = 0; i < 6; i++) wb[i] = (u16*)(ws + 2 * SZ_ACT + i * SZ_W);
  char* ybase = ws + 2 * SZ_ACT + 6 * SZ_W;
  u16* Y0 = (u16*)(ybase);                 // r_hidden; reused for c_hidden
  u16* Y1 = (u16*)(ybase + SZ_ACT);        // r_input;  reused for hr
  u16* Y2 = (u16*)(ybase + 2 * SZ_ACT);    // u_hidden
  u16* Y3 = (u16*)(ybase + 3 * SZ_ACT);    // u_input
  u16* Y5 = (u16*)(ybase + 4 * SZ_ACT);    // c_input

  // 1) one fused convert launch
  ConvAll ca = {};
  ca.src[0] = x; ca.dst[0] = xb;
  ca.src[1] = h; ca.dst[1] = hb;
  for (int i = 0; i < 6; i++) { ca.src[2 + i] = Ws[i]; ca.dst[2 + i] = wb[i]; }
  convert_all<<<16384 + 6 * 1024, 256, 0, stream>>>(ca);

  // 2) batched stage-1 GEMMs (XCD-swizzled): r_h, r_x, u_h, u_x, c_x
  GemmArgs g = {};
  g.A[0] = hb; g.Bw[0] = wb[0]; g.Y[0] = Y0;   // h @ W_r^T
  g.A[1] = xb; g.Bw[1] = wb[1]; g.Y[1] = Y1;   // x @ U_r^T
  g.A[2] = hb; g.Bw[2] = wb[2]; g.Y[2] = Y2;   // h @ W_u^T
  g.A[3] = xb; g.Bw[3] = wb[3]; g.Y[3] = Y3;   // x @ U_u^T
  g.A[4] = xb; g.Bw[4] = wb[5]; g.Y[4] = Y5;   // x @ U_c^T
  gemm_bt128<<<2560, 256, 0, stream>>>(g);

  // 3) r gate + hr (hr overwrites Y1; per-thread read-before-write)
  rgate_kernel<<<2048, 256, 0, stream>>>(Y0, Y1, hb, gamma, beta, Y1);

  // 4) c_hidden GEMM: hr @ W_c^T -> Y0 (Y0 dead after rgate)
  gemm_hr<<<1024, 256, 0, stream>>>(Y1, wb[4], Y0);

  // 5) u, c, out (h in fp32)
  final_fuse<<<2048, 256, 0, stream>>>(Y2, Y3, Y0, Y5, h, gamma, beta, out);
}